// Round 2
// baseline (659.231 us; speedup 1.0000x reference)
//
#include <hip/hip_runtime.h>
#include <hip/hip_bf16.h>
#include <stdint.h>

// Problem constants (fixed by the reference)
#define B_ 8
#define T_ 128
#define U_ 64
#define D_ 1024
#define V_ 1024
// M_total = B*T*U = 65536

typedef __attribute__((ext_vector_type(8))) short short8v;   // 8 bf16 (4 VGPRs)
typedef __attribute__((ext_vector_type(4))) float floatx4;   // MFMA accumulator

typedef __attribute__((address_space(3))) uint8_t lds_u8_t;
typedef __attribute__((address_space(1))) uint8_t glb_u8_t;

// fp32 -> bf16, round-to-nearest-even
__device__ __forceinline__ unsigned short f2bf(float f) {
  union { float f; uint32_t u; } c; c.f = f;
  const uint32_t u = c.u;
  return (unsigned short)((u + 0x7fffu + ((u >> 16) & 1u)) >> 16);
}

// ---------------------------------------------------------------------------
// prep_w: W[k][v] fp32  ->  Wt[v][k] bf16, pre-swizzled within each 64-k group
// so that the GEMM can global_load_lds linearly and ds_read with the
// byte ^= ((row&7)<<4) swizzle (T2/m201 pattern: linear dest + inverse-swz src).
// Grid: (D/64, V/64) blocks x 256 threads.
// ---------------------------------------------------------------------------
__global__ void prep_w(const float* __restrict__ W, unsigned short* __restrict__ Wt) {
  __shared__ float tile[64][65];           // [k][v], +1 pad
  const int k0 = blockIdx.x * 64;
  const int v0 = blockIdx.y * 64;
  const int tid = threadIdx.x;
#pragma unroll
  for (int c = 0; c < 4; ++c) {            // 1024 float4 slots, coalesced over v
    const int lin = tid + c * 256;
    const int kk = lin >> 4;
    const int vv = (lin & 15) << 2;
    const float4 f = *reinterpret_cast<const float4*>(&W[(size_t)(k0 + kk) * V_ + v0 + vv]);
    tile[kk][vv + 0] = f.x; tile[kk][vv + 1] = f.y;
    tile[kk][vv + 2] = f.z; tile[kk][vv + 3] = f.w;
  }
  __syncthreads();
#pragma unroll
  for (int c = 0; c < 2; ++c) {            // 512 chunk-writes of 8 bf16 (16B)
    const int w = tid + c * 256;
    const int vv = w >> 3;                 // v within tile
    const int p  = w & 7;                  // stored chunk position in row
    const int lc = p ^ (vv & 7);           // logical k-chunk held at position p
    short8v val;
#pragma unroll
    for (int j = 0; j < 8; ++j) val[j] = (short)f2bf(tile[lc * 8 + j][vv]);
    *reinterpret_cast<short8v*>(&Wt[(size_t)(v0 + vv) * D_ + k0 + p * 8]) = val;
  }
}

// ---------------------------------------------------------------------------
// joiner_gemm: 128x128 output tile per block, BK=64, 4 waves (2x2, 64x64 each),
// mfma_f32_16x16x32_bf16, 4x4 fragments per wave.
// A-tile computed on the fly: A[r][k] = relu(src[b][t0 + r/64][k] + tgt[b][r&63][k])
// ---------------------------------------------------------------------------
__global__ __launch_bounds__(256) void joiner_gemm(
    const float* __restrict__ src, const float* __restrict__ tgt,
    const unsigned short* __restrict__ Wt, const float* __restrict__ bias,
    float* __restrict__ out)
{
  __shared__ __align__(16) short As[128 * 64];   // swizzled: row*64 + (chunk^(row&7))*8
  __shared__ __align__(16) short Ws[128 * 64];   // linear copy of pre-swizzled Wt rows

  const int tid  = threadIdx.x;
  const int lane = tid & 63;
  const int wid  = tid >> 6;
  const int wm   = wid & 1;          // wave row (2)
  const int wn   = wid >> 1;         // wave col (2)
  const int l15  = lane & 15;
  const int l4   = lane >> 4;

  const int bid    = blockIdx.x;
  const int nt     = bid & 7;        // 8 n-tiles
  const int mt     = bid >> 3;       // 512 m-tiles
  const int m_base = mt << 7;
  const int bb     = m_base >> 13;            // / (T*U)
  const int t0     = (m_base & 8191) >> 6;    // / U
  const int v0     = nt << 7;

  // A staging assignment: thread -> (row, k-half)
  const int arow = tid >> 1;                  // 0..127
  const int akh  = (tid & 1) << 5;            // 0 or 32
  const float* srow = src + (size_t)(bb * T_ + t0 + (arow >> 6)) * D_;
  const float* trow = tgt + (size_t)(bb * U_ + (arow & 63)) * D_;
  const int aswz = arow & 7;

  floatx4 acc[4][4] = {};

  for (int ks = 0; ks < 16; ++ks) {
    const int k0 = ks << 6;

    // ---- stage A: compute 32 elems/thread, swizzled 16B ds_writes
#pragma unroll
    for (int c = 0; c < 4; ++c) {
      const int koff = akh + c * 8;
      const float4 s0 = *reinterpret_cast<const float4*>(srow + k0 + koff);
      const float4 s1 = *reinterpret_cast<const float4*>(srow + k0 + koff + 4);
      const float4 g0 = *reinterpret_cast<const float4*>(trow + k0 + koff);
      const float4 g1 = *reinterpret_cast<const float4*>(trow + k0 + koff + 4);
      short8v v;
      v[0] = (short)f2bf(fmaxf(s0.x + g0.x, 0.0f));
      v[1] = (short)f2bf(fmaxf(s0.y + g0.y, 0.0f));
      v[2] = (short)f2bf(fmaxf(s0.z + g0.z, 0.0f));
      v[3] = (short)f2bf(fmaxf(s0.w + g0.w, 0.0f));
      v[4] = (short)f2bf(fmaxf(s1.x + g1.x, 0.0f));
      v[5] = (short)f2bf(fmaxf(s1.y + g1.y, 0.0f));
      v[6] = (short)f2bf(fmaxf(s1.z + g1.z, 0.0f));
      v[7] = (short)f2bf(fmaxf(s1.w + g1.w, 0.0f));
      const int pos = (koff >> 3) ^ aswz;
      *reinterpret_cast<short8v*>(&As[arow * 64 + pos * 8]) = v;
    }

    // ---- stage W: linear global_load_lds (16B) from pre-swizzled Wt
#pragma unroll
    for (int c = 0; c < 4; ++c) {
      const int chunk = (wid << 8) + (c << 6) + lane;   // 0..1023 16B-chunks
      const int row   = chunk >> 3;
      const int pc    = chunk & 7;
      const unsigned short* g = Wt + (size_t)(v0 + row) * D_ + k0 + pc * 8;
      __builtin_amdgcn_global_load_lds((const glb_u8_t*)g, (lds_u8_t*)&Ws[chunk * 8], 16, 0, 0);
    }

    __syncthreads();   // drains lgkmcnt (ds_write) and vmcnt (global_load_lds)

    // ---- compute: 2 k-chunks of 32, 16 MFMAs each
#pragma unroll
    for (int kk = 0; kk < 2; ++kk) {
      short8v af[4], bf[4];
#pragma unroll
      for (int mi = 0; mi < 4; ++mi) {
        const int row = (wm << 6) + (mi << 4) + l15;
        const int pos = ((kk << 2) + l4) ^ (row & 7);
        af[mi] = *reinterpret_cast<const short8v*>(&As[row * 64 + pos * 8]);
      }
#pragma unroll
      for (int ni = 0; ni < 4; ++ni) {
        const int row = (wn << 6) + (ni << 4) + l15;
        const int pos = ((kk << 2) + l4) ^ (row & 7);
        bf[ni] = *reinterpret_cast<const short8v*>(&Ws[row * 64 + pos * 8]);
      }
#pragma unroll
      for (int mi = 0; mi < 4; ++mi)
#pragma unroll
        for (int ni = 0; ni < 4; ++ni)
          acc[mi][ni] = __builtin_amdgcn_mfma_f32_16x16x32_bf16(af[mi], bf[ni], acc[mi][ni], 0, 0, 0);
    }

    __syncthreads();   // protect LDS before next iteration's staging
  }

  // ---- epilogue: D row = (lane>>4)*4 + reg, col = lane&15
  const int gcbase = v0 + (wn << 6);
#pragma unroll
  for (int ni = 0; ni < 4; ++ni) {
    const int gc = gcbase + (ni << 4) + l15;
    const float bv = bias[gc];
#pragma unroll
    for (int mi = 0; mi < 4; ++mi) {
      const int gr = m_base + (wm << 6) + (mi << 4) + (l4 << 2);
      float* o = out + (size_t)gr * V_ + gc;
#pragma unroll
      for (int r = 0; r < 4; ++r)
        o[(size_t)r * V_] = acc[mi][ni][r] + bv;
    }
  }
}

extern "C" void kernel_launch(void* const* d_in, const int* in_sizes, int n_in,
                              void* d_out, int out_size, void* d_ws, size_t ws_size,
                              hipStream_t stream) {
  const float* src  = (const float*)d_in[0];   // (B,T,D)
  const float* tgt  = (const float*)d_in[1];   // (B,U,D)
  const float* W    = (const float*)d_in[2];   // (D,V)
  const float* bias = (const float*)d_in[3];   // (V,)
  float* out = (float*)d_out;                  // (B,T,U,V) fp32
  unsigned short* Wt = (unsigned short*)d_ws;  // 2 MB bf16 scratch

  // 1) convert + transpose + pre-swizzle W
  prep_w<<<dim3(D_ / 64, V_ / 64), 256, 0, stream>>>(W, Wt);

  // 2) fused joiner GEMM: grid = (M/128) * (V/128)
  const int grid = (65536 / 128) * (V_ / 128);
  joiner_gemm<<<grid, 256, 0, stream>>>(src, tgt, Wt, bias, out);
}